// Round 6
// baseline (981.532 us; speedup 1.0000x reference)
//
#include <hip/hip_runtime.h>
#include <hip/hip_bf16.h>
#include <math.h>

#define N_NODES 20000
#define N_EDGES 200000
#define XROW    1480   // EMB + MD

typedef __attribute__((ext_vector_type(8))) _Float16 f16x8;
typedef __attribute__((ext_vector_type(8))) unsigned short u16x8;
typedef __attribute__((ext_vector_type(4))) float f32x4v;

// ---------------- reduction helpers ----------------
__device__ __forceinline__ float wsum(float v){
#pragma unroll
  for (int o=32;o>0;o>>=1) v += __shfl_down(v,o);
  return v;
}
__device__ __forceinline__ float wmax(float v){
#pragma unroll
  for (int o=32;o>0;o>>=1) v = fmaxf(v,__shfl_down(v,o));
  return v;
}
// butterfly: result in ALL lanes
__device__ __forceinline__ float wsum_all(float v){
#pragma unroll
  for (int o=32;o>0;o>>=1) v += __shfl_xor(v,o);
  return v;
}
__device__ __forceinline__ float wmax_all(float v){
#pragma unroll
  for (int o=32;o>0;o>>=1) v = fmaxf(v,__shfl_xor(v,o));
  return v;
}

__device__ __forceinline__ unsigned short f2hu(float f){
  _Float16 h = (_Float16)f;
  return __builtin_bit_cast(unsigned short, h);
}
__device__ __forceinline__ float hu2f(unsigned short u){
  return (float)__builtin_bit_cast(_Float16, u);
}

__device__ __forceinline__ void async_copy16(void* lds, const void* g){
  __builtin_amdgcn_global_load_lds((const __attribute__((address_space(1))) void*)g,
                                   (__attribute__((address_space(3))) void*)lds, 16, 0, 0);
}

// ---------------- edge preprocessing (once, reused 3 layers) ----------------
__global__ void edge_count_kernel(const int* __restrict__ ei, const float* __restrict__ ea,
                                  int* __restrict__ cnt, float* __restrict__ easum, int E){
  int e = blockIdx.x*256 + threadIdx.x;
  if (e >= E) return;
  int dst = ei[E + e];
  atomicAdd(&cnt[dst], 1);
  atomicAdd(&easum[dst], ea[e]);
}

__launch_bounds__(1024)
__global__ void scan_kernel(const int* __restrict__ cnt, const float* __restrict__ easum,
                            int* __restrict__ off, float* __restrict__ loop_attr, int n){
  __shared__ int buf[1024];
  __shared__ int carry_s;
  if (threadIdx.x==0) carry_s = 0;
  __syncthreads();
  for (int base=0; base<n; base+=1024){
    int i = base + threadIdx.x;
    int v = (i<n)? cnt[i] : 0;
    if (i<n){
      loop_attr[i] = (v>0) ? easum[i]/(float)v : 0.f;  // fill='mean'
    }
    buf[threadIdx.x] = v;
    __syncthreads();
    for (int d2=1; d2<1024; d2<<=1){
      int tv = (threadIdx.x>=d2)? buf[threadIdx.x-d2] : 0;
      __syncthreads();
      buf[threadIdx.x] += tv;
      __syncthreads();
    }
    if (i<n) off[i] = carry_s + buf[threadIdx.x] - v;   // exclusive
    int tot = buf[1023];
    __syncthreads();
    if (threadIdx.x==0) carry_s += tot;
    __syncthreads();
  }
  if (threadIdx.x==0) off[n] = carry_s;
}

__global__ void edge_fill_kernel(const int* __restrict__ ei, const float* __restrict__ ea,
                                 const int* __restrict__ off, int* __restrict__ fill,
                                 int* __restrict__ csr_src, float* __restrict__ csr_ea, int E){
  int e = blockIdx.x*256 + threadIdx.x;
  if (e >= E) return;
  int dst = ei[E + e];
  int pos = off[dst] + atomicAdd(&fill[dst], 1);
  csr_src[pos] = ei[e];
  csr_ea[pos]  = ea[e];
}

// ---------------- conversions ----------------
// x[:, :1280] f32 -> f16 (row-major, stride 1280)
__global__ void x_to_f16(const float* __restrict__ x, unsigned short* __restrict__ xh){
  const int CH4 = 1280/4; // 320 float4 per row
  long total = (long)N_NODES*CH4;
  for (long i = (long)blockIdx.x*256 + threadIdx.x; i < total; i += (long)gridDim.x*256){
    int row = (int)(i / CH4), c4 = (int)(i % CH4);
    float4 v = *(const float4*)(x + (size_t)row*XROW + c4*4);
    ushort4 o;
    o.x = f2hu(v.x); o.y = f2hu(v.y); o.z = f2hu(v.z); o.w = f2hu(v.w);
    *(ushort4*)(xh + (size_t)row*1280 + c4*4) = o;
  }
}

// transpose: W[K,N] f32 -> Wt[N,K] f16
__global__ void wt_f16_kernel(const float* __restrict__ W, int K, int N,
                              unsigned short* __restrict__ Wt){
  __shared__ float tile[32][33];
  int k0 = blockIdx.x*32, n0 = blockIdx.y*32;
  int tx = threadIdx.x & 31, ty = threadIdx.x >> 5; // 32 x 8
  for (int r=ty; r<32; r+=8) tile[r][tx] = W[(size_t)(k0+r)*N + n0+tx];
  __syncthreads();
  for (int r=ty; r<32; r+=8){
    float w = tile[tx][r];               // = W[k0+tx][n0+r]
    Wt[(size_t)(n0+r)*K + k0+tx] = f2hu(w);
  }
}

// ---------------- cross-attention (rank-1 collapsed) ----------------
__global__ void kv_kernel(const float* __restrict__ x,
                          const float* __restrict__ kw, const float* __restrict__ kb,
                          const float* __restrict__ vw, const float* __restrict__ vb,
                          float* __restrict__ Kv, float* __restrict__ Vv){
  int j = threadIdx.x; // 256
  float ka = kb[j], va = vb[j];
  for (int k=0;k<200;k++){
    float m = x[1280+k];
    ka = fmaf(m, kw[k*256+j], ka);
    va = fmaf(m, vw[k*256+j], va);
  }
  Kv[j]=ka; Vv[j]=va;
}

__global__ void qkvo_kernel(const float* __restrict__ qw, const float* __restrict__ ow,
                            const float* __restrict__ Kv, const float* __restrict__ Vv,
                            float* __restrict__ qK, float* __restrict__ Vo){
  int idx = blockIdx.x*256 + threadIdx.x;
  if (idx < 1280){
    float a=0;
    for (int j=0;j<256;j++) a = fmaf(qw[idx*256+j], Kv[j], a);
    qK[idx]=a;
  } else if (idx < 2560){
    int j = idx-1280;
    float a=0;
    for (int i=0;i<256;i++) a = fmaf(Vv[i], ow[(size_t)i*1280+j], a);
    Vo[j]=a;
  }
}

__global__ void obw_kernel(const float* __restrict__ ob, const float* __restrict__ Vo,
                           const float* __restrict__ W, float* __restrict__ obW, float* __restrict__ VoW){
  int j = blockIdx.x*256 + threadIdx.x; // < 1024
  float a=0,b=0;
  for (int i=0;i<1280;i++){
    float w = W[(size_t)i*1024+j];
    a = fmaf(ob[i], w, a);
    b = fmaf(Vo[i], w, b);
  }
  obW[j]=a; VoW[j]=b;
}

__launch_bounds__(256)
__global__ void scores_kernel(const float* __restrict__ x, const float* __restrict__ qK,
                              float* __restrict__ scores, int n){
  __shared__ float qs[1280];
  int t = threadIdx.x;
  for (int i=t;i<1280;i+=256) qs[i]=qK[i];
  __syncthreads();
  int wid = t>>6, lane = t&63;
  int node = blockIdx.x*4 + wid;
  if (node >= n) return;
  const float4* row = (const float4*)(x + (size_t)node*XROW);
  float acc = 0;
#pragma unroll
  for (int it=0; it<5; it++){
    float4 v = row[lane + 64*it];
    float4 q = *(const float4*)&qs[4*(lane+64*it)];
    acc += v.x*q.x + v.y*q.y + v.z*q.z + v.w*q.w;
  }
  acc = wsum(acc);
  if (lane==0) scores[node] = acc;
}

__launch_bounds__(1024)
__global__ void softmax_nodes(const float* __restrict__ scores, float* __restrict__ wts, int n){
  __shared__ float red[16];
  int t = threadIdx.x, lane=t&63, wid=t>>6;
  float m = -INFINITY;
  for (int i=t;i<n;i+=1024) m = fmaxf(m, scores[i]);
  m = wmax(m);
  if (lane==0) red[wid]=m;
  __syncthreads();
  if (t==0){ float r=red[0]; for (int k=1;k<16;k++) r=fmaxf(r,red[k]); red[0]=r; }
  __syncthreads();
  float M = red[0];
  __syncthreads();
  float z=0;
  for (int i=t;i<n;i+=1024) z += expf((scores[i]-M)*(1.f/16.f));
  z = wsum(z);
  if (lane==0) red[wid]=z;
  __syncthreads();
  if (t==0){ float r=0; for (int k=0;k<16;k++) r+=red[k]; red[0]=r; }
  __syncthreads();
  float invZ = 1.f/red[0];
  for (int i=t;i<n;i+=1024) wts[i] = expf((scores[i]-M)*(1.f/16.f))*invZ;
}

// ---------------- f16 MFMA GEMM (TN): C[M,N] = A[M,K] @ B[N,K]^T ----------------
// 128x128 tile, BK=64, 256 threads (4 waves, 2x2 of 64x64), 16x16x32 f16 MFMA.
// XCD-aware swizzle: lin%8 == blockIdx.x == XCD; M-band = bx + 8*(by/ntc),
// N-tile = by%ntc -> all N-tiles of a band run consecutively on ONE XCD
// (A-band fetched into one L2 once). Fused als/ald epilogue (a 128-col tile
// lies in exactly one head).
__launch_bounds__(256)
__global__ void gemm_f16(const unsigned short* __restrict__ A,
                         const unsigned short* __restrict__ B,
                         unsigned short* __restrict__ C, int M, int N, int K,
                         const float* __restrict__ addCol,   // obW or null
                         const float* __restrict__ vCol,     // VoW
                         const float* __restrict__ wRow,     // wts
                         const float* __restrict__ a_src,    // [H*256] flat
                         const float* __restrict__ a_dst,
                         float* __restrict__ als,            // [M*H] (pre-zeroed)
                         float* __restrict__ ald,
                         int H)
{
  __shared__ short lds[2*128*64];
  short* As = lds;
  short* Bs = lds + 128*64;

  const int ntc = N >> 7;                 // N-tiles (pow2: 8 or 2)
  const int sh  = __popc(ntc - 1);
  const int g   = blockIdx.y >> sh;
  const int nt  = blockIdx.y & (ntc - 1);
  const int band = blockIdx.x + (g << 3); // bx + 8*g
  if (band * 128 >= M) return;

  const int t = threadIdx.x;
  const int w = t>>6, l = t&63;
  const int bm = band*128, bn = nt*128;
  const int wr = (w>>1)*64, wc = (w&1)*64;

  f32x4v acc[4][4];
#pragma unroll
  for (int i=0;i<4;i++)
#pragma unroll
    for (int j=0;j<4;j++) acc[i][j] = (f32x4v){0.f,0.f,0.f,0.f};

  const unsigned short* Ap[4]; const unsigned short* Bp[4];
  int ldsOff[4];
#pragma unroll
  for (int q=0;q<4;q++){
    int p  = (w*4+q)*64 + l;       // phys 16B-chunk
    int r  = p>>3, pc = p&7;
    int kc = (pc ^ (r&7))*8;       // logical k element offset (XOR swizzle)
    int rowA = bm + r; if (rowA > M-1) rowA = M-1;
    Ap[q] = A + (size_t)rowA*K + kc;
    Bp[q] = B + (size_t)(bn+r)*K + kc;
    ldsOff[q] = (w*4+q)*64*8;      // shorts (wave-uniform base; lane spreads x16B)
  }

  for (int k0=0; k0<K; k0+=64){
#pragma unroll
    for (int q=0;q<4;q++) async_copy16(As + ldsOff[q], Ap[q] + k0);
#pragma unroll
    for (int q=0;q<4;q++) async_copy16(Bs + ldsOff[q], Bp[q] + k0);
    __syncthreads();

    const int q4 = l>>4, m16 = l&15;
#pragma unroll
    for (int ks=0; ks<2; ks++){
      f16x8 af[4], bf[4];
      const int c = ks*4 + q4;
#pragma unroll
      for (int i=0;i<4;i++){
        int ra = wr + i*16 + m16;
        af[i] = *(const f16x8*)&As[ra*64 + ((c ^ (ra&7))*8)];
        int rb = wc + i*16 + m16;
        bf[i] = *(const f16x8*)&Bs[rb*64 + ((c ^ (rb&7))*8)];
      }
#pragma unroll
      for (int i=0;i<4;i++)
#pragma unroll
        for (int j=0;j<4;j++)
          acc[i][j] = __builtin_amdgcn_mfma_f32_16x16x32_f16(af[i], bf[j], acc[i][j], 0,0,0);
    }
    __syncthreads();
  }

  // epilogue: C/D layout col = l&15, row = (l>>4)*4 + r ; f32 math then f16 store
  // + fused per-row dot with a_src/a_dst (this tile's head) -> atomic als/ald
  const int q4 = l>>4, m16 = l&15;
  const int hd = (bn + wc) >> 8;          // head of this wave's column range
  float asv[4], adv[4];
#pragma unroll
  for (int j=0;j<4;j++){
    int n = bn + wc + j*16 + m16;
    asv[j] = a_src[n];
    adv[j] = a_dst[n];
  }
#pragma unroll
  for (int i=0;i<4;i++){
#pragma unroll
    for (int r=0;r<4;r++){
      int m = bm + wr + i*16 + q4*4 + r;
      if (m >= M) continue;               // uniform within the 16-lane row group
      float wrow = addCol ? wRow[m] : 0.f;
      unsigned short* crow = C + (size_t)m*N;
      float vj[4];
#pragma unroll
      for (int j=0;j<4;j++){
        int n = bn + wc + j*16 + m16;
        float v = acc[i][j][r];
        if (addCol) v += addCol[n] + wrow*vCol[n];
        vj[j] = v;
        crow[n] = f2hu(v);
      }
      float s = vj[0]*asv[0] + vj[1]*asv[1] + vj[2]*asv[2] + vj[3]*asv[3];
      float d = vj[0]*adv[0] + vj[1]*adv[1] + vj[2]*adv[2] + vj[3]*adv[3];
#pragma unroll
      for (int o=1;o<16;o<<=1){ s += __shfl_xor(s,o); d += __shfl_xor(d,o); }
      if (m16 == 0){
        atomicAdd(&als[(size_t)m*H + hd], s);
        atomicAdd(&ald[(size_t)m*H + hd], d);
      }
    }
  }
}

template<int H>
__global__ void we_kernel(const float* __restrict__ We, const float* __restrict__ a_edge,
                          float* __restrict__ we){
  int wid = threadIdx.x>>6, lane = threadIdx.x&63;
  if (wid < H){
    const float4* w4 = (const float4*)(We + wid*256);
    const float4* a4 = (const float4*)(a_edge + wid*256);
    float4 a = w4[lane], b = a4[lane];
    float v = a.x*b.x + a.y*b.y + a.z*b.z + a.w*b.w;
    v = wsum(v);
    if (lane==0) we[wid]=v;
  }
}

// ---------------- fused alpha-softmax + aggregate + bias + LN + ReLU ----------------
// ONE WAVE PER NODE (4 waves/block, no __syncthreads). h is f16.
// outb != null -> write f16 (feeds next GEMM); else f32 to outf.
template<int H>
__launch_bounds__(256)
__global__ void gat_agg_ln_wave(const unsigned short* __restrict__ hmat,
                           const float* __restrict__ als, const float* __restrict__ ald,
                           const int* __restrict__ off, const int* __restrict__ csr_src,
                           const float* __restrict__ csr_ea, const float* __restrict__ loop_attr,
                           const float* __restrict__ we,
                           const float* __restrict__ bias,
                           const float* __restrict__ ln_g, const float* __restrict__ ln_b,
                           float* __restrict__ outf, unsigned short* __restrict__ outb, int n)
{
  constexpr int OUT = 256*H;      // 1024 or 256
  constexpr int CPL = OUT/64;     // channels per lane: 16 or 4
  const int wv = threadIdx.x>>6, lane = threadIdx.x&63;
  const int i = blockIdx.x*4 + wv;
  __shared__ float wbuf_s[4][64*H];
  __shared__ int   sbuf_s[4][64];
  if (i >= n) return;
  float* wbuf = wbuf_s[wv];
  int*   sbuf = sbuf_s[wv];

  const int begin = off[i];
  const int deg   = off[i+1]-begin;
  const int S     = deg + 1;           // + self-loop

  float aldi[H], wei[H];
#pragma unroll
  for (int hh=0;hh<H;hh++){ aldi[hh]=ald[(size_t)i*H+hh]; wei[hh]=we[hh]; }
  const float lea = loop_attr[i];

  const int head = (lane*CPL) >> 8;    // which head this lane's channels belong to
  const int c0   = lane*CPL;
  float acc[CPL];
#pragma unroll
  for (int c=0;c<CPL;c++) acc[c]=0.f;

  if (S <= 64){
    // ---- fast path: lane == edge slot; alphas live in registers ----
    int src = i; float ev = lea;
    if (lane < deg){ src = csr_src[begin+lane]; ev = csr_ea[begin+lane]; }
    const bool act = lane < S;
    float a[H];
#pragma unroll
    for (int hh=0;hh<H;hh++){
      float v = als[(size_t)src*H+hh] + aldi[hh] + ev*wei[hh];
      a[hh] = v>0.f ? v : 0.2f*v;
    }
#pragma unroll
    for (int hh=0;hh<H;hh++){
      float M = wmax_all(act ? a[hh] : -INFINITY);
      float e = act ? __expf(a[hh]-M) : 0.f;
      float Z = wsum_all(e);
      wbuf[lane*H+hh] = e / (Z + 1e-16f);
    }
    sbuf[lane] = src;
    for (int j=0;j<S;j++){
      int sj = sbuf[j];
      float wj = wbuf[j*H+head];
      const unsigned short* row = hmat + (size_t)sj*OUT + c0;
      if constexpr (CPL==16){
        u16x8 r0 = *(const u16x8*)(row);
        u16x8 r1 = *(const u16x8*)(row+8);
#pragma unroll
        for (int c=0;c<8;c++){
          acc[c]   = fmaf(wj, hu2f(r0[c]), acc[c]);
          acc[8+c] = fmaf(wj, hu2f(r1[c]), acc[8+c]);
        }
      } else {
        ushort4 r = *(const ushort4*)(row);
        acc[0]=fmaf(wj,hu2f(r.x),acc[0]); acc[1]=fmaf(wj,hu2f(r.y),acc[1]);
        acc[2]=fmaf(wj,hu2f(r.z),acc[2]); acc[3]=fmaf(wj,hu2f(r.w),acc[3]);
      }
    }
  } else {
    // ---- slow path (deg >= 64, vanishingly rare): chunked recompute ----
    float rm[H];
#pragma unroll
    for (int hh=0;hh<H;hh++) rm[hh] = -INFINITY;
    for (int s=lane; s<S; s+=64){
      int src = (s<deg)? csr_src[begin+s] : i;
      float ev = (s<deg)? csr_ea[begin+s] : lea;
#pragma unroll
      for (int hh=0;hh<H;hh++){
        float v = als[(size_t)src*H+hh] + aldi[hh] + ev*wei[hh];
        v = v>0.f? v : 0.2f*v;
        rm[hh] = fmaxf(rm[hh], v);
      }
    }
    float M[H], es[H];
#pragma unroll
    for (int hh=0;hh<H;hh++){ M[hh]=wmax_all(rm[hh]); es[hh]=0.f; }
    for (int s=lane; s<S; s+=64){
      int src = (s<deg)? csr_src[begin+s] : i;
      float ev = (s<deg)? csr_ea[begin+s] : lea;
#pragma unroll
      for (int hh=0;hh<H;hh++){
        float v = als[(size_t)src*H+hh] + aldi[hh] + ev*wei[hh];
        v = v>0.f? v : 0.2f*v;
        es[hh] += __expf(v - M[hh]);
      }
    }
    float invZ[H];
#pragma unroll
    for (int hh=0;hh<H;hh++) invZ[hh] = 1.f/(wsum_all(es[hh]) + 1e-16f);
    for (int cb=0; cb<S; cb+=64){
      int m = min(64, S-cb);
      int s = cb + lane;
      if (s < S){
        int src = (s<deg)? csr_src[begin+s] : i;
        float ev = (s<deg)? csr_ea[begin+s] : lea;
        sbuf[lane] = src;
#pragma unroll
        for (int hh=0;hh<H;hh++){
          float v = als[(size_t)src*H+hh] + aldi[hh] + ev*wei[hh];
          v = v>0.f? v : 0.2f*v;
          wbuf[lane*H+hh] = __expf(v - M[hh]) * invZ[hh];
        }
      }
      for (int j=0;j<m;j++){
        int sj = sbuf[j];
        float wj = wbuf[j*H+head];
        const unsigned short* row = hmat + (size_t)sj*OUT + c0;
        if constexpr (CPL==16){
          u16x8 r0 = *(const u16x8*)(row);
          u16x8 r1 = *(const u16x8*)(row+8);
#pragma unroll
          for (int c=0;c<8;c++){
            acc[c]   = fmaf(wj, hu2f(r0[c]), acc[c]);
            acc[8+c] = fmaf(wj, hu2f(r1[c]), acc[8+c]);
          }
        } else {
          ushort4 r = *(const ushort4*)(row);
          acc[0]=fmaf(wj,hu2f(r.x),acc[0]); acc[1]=fmaf(wj,hu2f(r.y),acc[1]);
          acc[2]=fmaf(wj,hu2f(r.z),acc[2]); acc[3]=fmaf(wj,hu2f(r.w),acc[3]);
        }
      }
    }
  }

  // ---- bias + LayerNorm + ReLU (wave-level) ----
  float vals[CPL];
  float ls=0.f;
#pragma unroll
  for (int c=0;c<CPL;c+=4){
    float4 b4 = *(const float4*)(bias + c0 + c);
    vals[c]=acc[c]+b4.x; vals[c+1]=acc[c+1]+b4.y; vals[c+2]=acc[c+2]+b4.z; vals[c+3]=acc[c+3]+b4.w;
    ls += vals[c]+vals[c+1]+vals[c+2]+vals[c+3];
  }
  float mu = wsum_all(ls) * (1.f/OUT);
  float lv=0.f;
#pragma unroll
  for (int c=0;c<CPL;c++){ float d=vals[c]-mu; lv += d*d; }
  float inv = rsqrtf(wsum_all(lv)*(1.f/OUT) + 1e-5f);

  if (outb){
#pragma unroll
    for (int c=0;c<CPL;c+=8){
      u16x8 o;
#pragma unroll
      for (int k=0;k<8;k++){
        float g = ln_g[c0+c+k], b = ln_b[c0+c+k];
        o[k] = f2hu(fmaxf((vals[c+k]-mu)*inv*g + b, 0.f));
      }
      *(u16x8*)(outb + (size_t)i*OUT + c0 + c) = o;
    }
    if constexpr (CPL==4){
      // CPL==4 handled below
    }
  }
  if (outb && CPL==4){
    ushort4 o;
    o.x = f2hu(fmaxf((vals[0]-mu)*inv*ln_g[c0+0] + ln_b[c0+0], 0.f));
    o.y = f2hu(fmaxf((vals[1]-mu)*inv*ln_g[c0+1] + ln_b[c0+1], 0.f));
    o.z = f2hu(fmaxf((vals[2]-mu)*inv*ln_g[c0+2] + ln_b[c0+2], 0.f));
    o.w = f2hu(fmaxf((vals[3]-mu)*inv*ln_g[c0+3] + ln_b[c0+3], 0.f));
    *(ushort4*)(outb + (size_t)i*OUT + c0) = o;
  }
  if (!outb){
#pragma unroll
    for (int c=0;c<CPL;c+=4){
      float4 g4 = *(const float4*)(ln_g + c0 + c);
      float4 b4 = *(const float4*)(ln_b + c0 + c);
      float4 o;
      o.x = fmaxf((vals[c+0]-mu)*inv*g4.x + b4.x, 0.f);
      o.y = fmaxf((vals[c+1]-mu)*inv*g4.y + b4.y, 0.f);
      o.z = fmaxf((vals[c+2]-mu)*inv*g4.z + b4.z, 0.f);
      o.w = fmaxf((vals[c+3]-mu)*inv*g4.w + b4.w, 0.f);
      *(float4*)(outf + (size_t)i*OUT + c0 + c) = o;
    }
  }
}

// ---------------- mean pool + classifier ----------------
__global__ void colsum_kernel(const float* __restrict__ h2, float* __restrict__ gsum, int n){
  int c = threadIdx.x; // 256
  float acc=0;
  for (int i=blockIdx.x;i<n;i+=gridDim.x) acc += h2[(size_t)i*256 + c];
  atomicAdd(&gsum[c], acc);
}

__launch_bounds__(128)
__global__ void cls_kernel(const float* __restrict__ gsum,
                           const float* __restrict__ w1, const float* __restrict__ b1,
                           const float* __restrict__ w2, const float* __restrict__ b2,
                           float* __restrict__ outp){
  __shared__ float g[256];
  __shared__ float hid[128];
  int t = threadIdx.x;
  g[t]     = gsum[t]    *(1.f/N_NODES);
  g[t+128] = gsum[t+128]*(1.f/N_NODES);
  __syncthreads();
  float a = b1[t];
  for (int c=0;c<256;c++) a = fmaf(g[c], w1[c*128+t], a);
  hid[t] = fmaxf(a, 0.f);
  __syncthreads();
  if (t<2){
    float o = b2[t];
    for (int j=0;j<128;j++) o = fmaf(hid[j], w2[j*2+t], o);
    outp[t] = o;
  }
}

// ---------------- launch ----------------
extern "C" void kernel_launch(void* const* d_in, const int* in_sizes, int n_in,
                              void* d_out, int out_size, void* d_ws, size_t ws_size,
                              hipStream_t stream)
{
  const float* x      = (const float*)d_in[0];
  const int*   ei     = (const int*)  d_in[1];
  const float* ea     = (const float*)d_in[2];
  const float* ca_qw  = (const float*)d_in[3];
  const float* ca_kw  = (const float*)d_in[5];
  const float* ca_kb  = (const float*)d_in[6];
  const float* ca_vw  = (const float*)d_in[7];
  const float* ca_vb  = (const float*)d_in[8];
  const float* ca_ow  = (const float*)d_in[9];
  const float* ca_ob  = (const float*)d_in[10];
  const float* g0_w   = (const float*)d_in[11];
  const float* g0_ew  = (const float*)d_in[12];
  const float* g0_as  = (const float*)d_in[13];
  const float* g0_ad  = (const float*)d_in[14];
  const float* g0_ae  = (const float*)d_in[15];
  const float* g0_b   = (const float*)d_in[16];
  const float* ln0_g  = (const float*)d_in[17];
  const float* ln0_b  = (const float*)d_in[18];
  const float* g1_w   = (const float*)d_in[19];
  const float* g1_ew  = (const float*)d_in[20];
  const float* g1_as  = (const float*)d_in[21];
  const float* g1_ad  = (const float*)d_in[22];
  const float* g1_ae  = (const float*)d_in[23];
  const float* g1_b   = (const float*)d_in[24];
  const float* ln1_g  = (const float*)d_in[25];
  const float* ln1_b  = (const float*)d_in[26];
  const float* g2_w   = (const float*)d_in[27];
  const float* g2_ew  = (const float*)d_in[28];
  const float* g2_as  = (const float*)d_in[29];
  const float* g2_ad  = (const float*)d_in[30];
  const float* g2_ae  = (const float*)d_in[31];
  const float* g2_b   = (const float*)d_in[32];
  const float* ln2_g  = (const float*)d_in[33];
  const float* ln2_b  = (const float*)d_in[34];
  const float* cls_w1 = (const float*)d_in[35];
  const float* cls_b1 = (const float*)d_in[36];
  const float* cls_w2 = (const float*)d_in[37];
  const float* cls_b2 = (const float*)d_in[38];
  float* outp = (float*)d_out;

  const int N = N_NODES, E = N_EDGES;

  char* base = (char*)d_ws;
  size_t o = 0;
  auto alloc = [&](size_t bytes)->void*{
    void* p = base + o;
    o += (bytes + 255) & ~(size_t)255;
    return p;
  };
  unsigned short* hF   = (unsigned short*)alloc((size_t)N*1024*2); // GEMM output h (f16)
  unsigned short* Af   = (unsigned short*)alloc((size_t)N*1280*2); // f16 activations (x, then agg out)
  float*          h2   = (float*)         alloc((size_t)N*256*4);  // layer-2 agg out (f32)
  unsigned short* Wt   = (unsigned short*)alloc((size_t)1280*1024*2);
  float* als       = (float*)alloc((size_t)2*N*4*4);  // als | ald contiguous
  float* ald       = als + (size_t)N*4;
  float* scores    = (float*)alloc((size_t)N*4);
  float* wts       = (float*)alloc((size_t)N*4);
  int*   cnt       = (int*)  alloc((size_t)N*4);
  float* easum     = (float*)alloc((size_t)N*4);
  int*   off       = (int*)  alloc((size_t)(N+1)*4);
  int*   fill      = (int*)  alloc((size_t)N*4);
  int*   csr_src   = (int*)  alloc((size_t)E*4);
  float* csr_ea    = (float*)alloc((size_t)E*4);
  float* loop_attr = (float*)alloc((size_t)N*4);
  float* Kv        = (float*)alloc(256*4);
  float* Vv        = (float*)alloc(256*4);
  float* qK        = (float*)alloc(1280*4);
  float* Vo        = (float*)alloc(1280*4);
  float* obW       = (float*)alloc(1024*4);
  float* VoW       = (float*)alloc(1024*4);
  float* web       = (float*)alloc(16*4);
  float* gsum      = (float*)alloc(256*4);

  hipMemsetAsync(cnt,   0, (size_t)N*4, stream);
  hipMemsetAsync(easum, 0, (size_t)N*4, stream);
  hipMemsetAsync(fill,  0, (size_t)N*4, stream);
  hipMemsetAsync(gsum,  0, 256*4,       stream);

  // ---- edge preprocessing (CSR by dst) ----
  int eblocks = (E + 255)/256;
  edge_count_kernel<<<eblocks,256,0,stream>>>(ei, ea, cnt, easum, E);
  scan_kernel<<<1,1024,0,stream>>>(cnt, easum, off, loop_attr, N);
  edge_fill_kernel<<<eblocks,256,0,stream>>>(ei, ea, off, fill, csr_src, csr_ea, E);

  // ---- activations to f16 ----
  x_to_f16<<<2048,256,0,stream>>>(x, Af);

  // ---- cross-attention, rank-1 collapsed ----
  kv_kernel<<<1,256,0,stream>>>(x, ca_kw, ca_kb, ca_vw, ca_vb, Kv, Vv);
  qkvo_kernel<<<10,256,0,stream>>>(ca_qw, ca_ow, Kv, Vv, qK, Vo);
  obw_kernel<<<4,256,0,stream>>>(ca_ob, Vo, g0_w, obW, VoW);
  scores_kernel<<<(N+3)/4,256,0,stream>>>(x, qK, scores, N);
  softmax_nodes<<<1,1024,0,stream>>>(scores, wts, N);

  const int mTiles  = (N + 127)/128;      // 157
  const int mGroups = (mTiles + 7)/8;     // 20
  const int NB4 = (N + 3)/4;              // wave-per-node blocks

  // ---- layer 0 ----
  wt_f16_kernel<<<dim3(1280/32, 1024/32),256,0,stream>>>(g0_w, 1280, 1024, Wt);
  hipMemsetAsync(als, 0, (size_t)2*N*4*4, stream);
  gemm_f16<<<dim3(8, mGroups*8),256,0,stream>>>(Af, Wt, hF, N, 1024, 1280, obW, VoW, wts,
                                                g0_as, g0_ad, als, ald, 4);
  we_kernel<4><<<1,256,0,stream>>>(g0_ew, g0_ae, web);
  gat_agg_ln_wave<4><<<NB4,256,0,stream>>>(hF, als, ald, off, csr_src, csr_ea, loop_attr,
                                           web, g0_b, ln0_g, ln0_b, nullptr, Af, N);

  // ---- layer 1 ----
  wt_f16_kernel<<<dim3(1024/32, 1024/32),256,0,stream>>>(g1_w, 1024, 1024, Wt);
  hipMemsetAsync(als, 0, (size_t)2*N*4*4, stream);
  gemm_f16<<<dim3(8, mGroups*8),256,0,stream>>>(Af, Wt, hF, N, 1024, 1024, nullptr, nullptr, nullptr,
                                                g1_as, g1_ad, als, ald, 4);
  we_kernel<4><<<1,256,0,stream>>>(g1_ew, g1_ae, web);
  gat_agg_ln_wave<4><<<NB4,256,0,stream>>>(hF, als, ald, off, csr_src, csr_ea, loop_attr,
                                           web, g1_b, ln1_g, ln1_b, nullptr, Af, N);

  // ---- layer 2 (1 head, 256 out) ----
  wt_f16_kernel<<<dim3(1024/32, 256/32),256,0,stream>>>(g2_w, 1024, 256, Wt);
  hipMemsetAsync(als, 0, (size_t)2*N*4*4, stream);
  gemm_f16<<<dim3(8, mGroups*2),256,0,stream>>>(Af, Wt, hF, N, 256, 1024, nullptr, nullptr, nullptr,
                                                g2_as, g2_ad, als, ald, 1);
  we_kernel<1><<<1,256,0,stream>>>(g2_ew, g2_ae, web);
  gat_agg_ln_wave<1><<<NB4,256,0,stream>>>(hF, als, ald, off, csr_src, csr_ea, loop_attr,
                                           web, g2_b, ln2_g, ln2_b, h2, nullptr, N);

  // ---- mean pool + classifier ----
  colsum_kernel<<<256,256,0,stream>>>(h2, gsum, N);
  cls_kernel<<<1,128,0,stream>>>(gsum, cls_w1, cls_b1, cls_w2, cls_b2, outp);

  (void)in_sizes; (void)n_in; (void)out_size; (void)ws_size;
}

// Round 7
// 901.911 us; speedup vs baseline: 1.0883x; 1.0883x over previous
//
#include <hip/hip_runtime.h>
#include <hip/hip_bf16.h>
#include <math.h>

#define N_NODES 20000
#define N_EDGES 200000
#define XROW    1480   // EMB + MD

typedef __attribute__((ext_vector_type(8))) _Float16 f16x8;
typedef __attribute__((ext_vector_type(8))) unsigned short u16x8;
typedef __attribute__((ext_vector_type(4))) float f32x4v;

// ---------------- reduction helpers ----------------
__device__ __forceinline__ float wsum(float v){
#pragma unroll
  for (int o=32;o>0;o>>=1) v += __shfl_down(v,o);
  return v;
}
__device__ __forceinline__ float wmax(float v){
#pragma unroll
  for (int o=32;o>0;o>>=1) v = fmaxf(v,__shfl_down(v,o));
  return v;
}
// butterfly: result in ALL lanes
__device__ __forceinline__ float wsum_all(float v){
#pragma unroll
  for (int o=32;o>0;o>>=1) v += __shfl_xor(v,o);
  return v;
}
__device__ __forceinline__ float wmax_all(float v){
#pragma unroll
  for (int o=32;o>0;o>>=1) v = fmaxf(v,__shfl_xor(v,o));
  return v;
}

__device__ __forceinline__ unsigned short f2hu(float f){
  _Float16 h = (_Float16)f;
  return __builtin_bit_cast(unsigned short, h);
}
__device__ __forceinline__ float hu2f(unsigned short u){
  return (float)__builtin_bit_cast(_Float16, u);
}

__device__ __forceinline__ void async_copy16(void* lds, const void* g){
  __builtin_amdgcn_global_load_lds((const __attribute__((address_space(1))) void*)g,
                                   (__attribute__((address_space(3))) void*)lds, 16, 0, 0);
}

// ---------------- edge preprocessing (once, reused 3 layers) ----------------
__global__ void edge_count_kernel(const int* __restrict__ ei, const float* __restrict__ ea,
                                  int* __restrict__ cnt, float* __restrict__ easum, int E){
  int e = blockIdx.x*256 + threadIdx.x;
  if (e >= E) return;
  int dst = ei[E + e];
  atomicAdd(&cnt[dst], 1);
  atomicAdd(&easum[dst], ea[e]);
}

// thread-serial chunk of 20 + single 1024 Kogge-Stone scan
__launch_bounds__(1024)
__global__ void scan_kernel(const int* __restrict__ cnt, const float* __restrict__ easum,
                            int* __restrict__ off, float* __restrict__ loop_attr, int n){
  __shared__ int buf[1024];
  const int PER = (N_NODES + 1023)/1024;   // 20
  int t = threadIdx.x;
  int base = t*PER;
  int local[PER];
  int s = 0;
#pragma unroll
  for (int k=0;k<PER;k++){
    int i = base + k;
    int v = (i<n)? cnt[i] : 0;
    local[k] = v;
    s += v;
  }
  buf[t] = s;
  __syncthreads();
  for (int d2=1; d2<1024; d2<<=1){
    int tv = (t>=d2)? buf[t-d2] : 0;
    __syncthreads();
    buf[t] += tv;
    __syncthreads();
  }
  int run = buf[t] - s;   // exclusive prefix of this thread's chunk
#pragma unroll
  for (int k=0;k<PER;k++){
    int i = base + k;
    if (i < n){
      off[i] = run;
      int v = local[k];
      loop_attr[i] = (v>0) ? easum[i]/(float)v : 0.f;  // fill='mean'
      run += v;
    }
  }
  if (t == 1023) off[n] = buf[1023];
}

__global__ void edge_fill_kernel(const int* __restrict__ ei, const float* __restrict__ ea,
                                 const int* __restrict__ off, int* __restrict__ fill,
                                 int* __restrict__ csr_src, float* __restrict__ csr_ea, int E){
  int e = blockIdx.x*256 + threadIdx.x;
  if (e >= E) return;
  int dst = ei[E + e];
  int pos = off[dst] + atomicAdd(&fill[dst], 1);
  csr_src[pos] = ei[e];
  csr_ea[pos]  = ea[e];
}

// ---------------- conversions ----------------
// x[:, :1280] f32 -> f16 (row-major, stride 1280)
__global__ void x_to_f16(const float* __restrict__ x, unsigned short* __restrict__ xh){
  const int CH4 = 1280/4; // 320 float4 per row
  long total = (long)N_NODES*CH4;
  for (long i = (long)blockIdx.x*256 + threadIdx.x; i < total; i += (long)gridDim.x*256){
    int row = (int)(i / CH4), c4 = (int)(i % CH4);
    float4 v = *(const float4*)(x + (size_t)row*XROW + c4*4);
    ushort4 o;
    o.x = f2hu(v.x); o.y = f2hu(v.y); o.z = f2hu(v.z); o.w = f2hu(v.w);
    *(ushort4*)(xh + (size_t)row*1280 + c4*4) = o;
  }
}

// transpose: W[K,N] f32 -> Wt[N,K] f16
__global__ void wt_f16_kernel(const float* __restrict__ W, int K, int N,
                              unsigned short* __restrict__ Wt){
  __shared__ float tile[32][33];
  int k0 = blockIdx.x*32, n0 = blockIdx.y*32;
  int tx = threadIdx.x & 31, ty = threadIdx.x >> 5; // 32 x 8
  for (int r=ty; r<32; r+=8) tile[r][tx] = W[(size_t)(k0+r)*N + n0+tx];
  __syncthreads();
  for (int r=ty; r<32; r+=8){
    float w = tile[tx][r];               // = W[k0+tx][n0+r]
    Wt[(size_t)(n0+r)*K + k0+tx] = f2hu(w);
  }
}

// ---------------- cross-attention (rank-1 collapsed) ----------------
__global__ void kv_kernel(const float* __restrict__ x,
                          const float* __restrict__ kw, const float* __restrict__ kb,
                          const float* __restrict__ vw, const float* __restrict__ vb,
                          float* __restrict__ Kv, float* __restrict__ Vv){
  int j = threadIdx.x; // 256
  float ka = kb[j], va = vb[j];
  for (int k=0;k<200;k++){
    float m = x[1280+k];
    ka = fmaf(m, kw[k*256+j], ka);
    va = fmaf(m, vw[k*256+j], va);
  }
  Kv[j]=ka; Vv[j]=va;
}

__global__ void qkvo_kernel(const float* __restrict__ qw, const float* __restrict__ ow,
                            const float* __restrict__ Kv, const float* __restrict__ Vv,
                            float* __restrict__ qK, float* __restrict__ Vo){
  int idx = blockIdx.x*256 + threadIdx.x;
  if (idx < 1280){
    float a=0;
    for (int j=0;j<256;j++) a = fmaf(qw[idx*256+j], Kv[j], a);
    qK[idx]=a;
  } else if (idx < 2560){
    int j = idx-1280;
    float a=0;
    for (int i=0;i<256;i++) a = fmaf(Vv[i], ow[(size_t)i*1280+j], a);
    Vo[j]=a;
  }
}

__global__ void obw_kernel(const float* __restrict__ ob, const float* __restrict__ Vo,
                           const float* __restrict__ W, float* __restrict__ obW, float* __restrict__ VoW){
  int j = blockIdx.x*256 + threadIdx.x; // < 1024
  float a=0,b=0;
  for (int i=0;i<1280;i++){
    float w = W[(size_t)i*1024+j];
    a = fmaf(ob[i], w, a);
    b = fmaf(Vo[i], w, b);
  }
  obW[j]=a; VoW[j]=b;
}

// scores from f16 activations (1280 halves per row)
__launch_bounds__(256)
__global__ void scores_kernel(const unsigned short* __restrict__ xh, const float* __restrict__ qK,
                              float* __restrict__ scores, int n){
  __shared__ float qs[1280];
  int t = threadIdx.x;
  for (int i=t;i<1280;i+=256) qs[i]=qK[i];
  __syncthreads();
  int wid = t>>6, lane = t&63;
  int node = blockIdx.x*4 + wid;
  if (node >= n) return;
  const u16x8* row = (const u16x8*)(xh + (size_t)node*1280);  // 160 chunks
  float acc = 0;
#pragma unroll
  for (int it=0; it<3; it++){
    int chunk = it*64 + lane;
    if (chunk < 160){
      u16x8 v = row[chunk];
#pragma unroll
      for (int k=0;k<8;k++) acc = fmaf(hu2f(v[k]), qs[chunk*8+k], acc);
    }
  }
  acc = wsum(acc);
  if (lane==0) scores[node] = acc;
}

__launch_bounds__(1024)
__global__ void softmax_nodes(const float* __restrict__ scores, float* __restrict__ wts, int n){
  __shared__ float red[16];
  int t = threadIdx.x, lane=t&63, wid=t>>6;
  float m = -INFINITY;
  for (int i=t;i<n;i+=1024) m = fmaxf(m, scores[i]);
  m = wmax(m);
  if (lane==0) red[wid]=m;
  __syncthreads();
  if (t==0){ float r=red[0]; for (int k=1;k<16;k++) r=fmaxf(r,red[k]); red[0]=r; }
  __syncthreads();
  float M = red[0];
  __syncthreads();
  float z=0;
  for (int i=t;i<n;i+=1024) z += expf((scores[i]-M)*(1.f/16.f));
  z = wsum(z);
  if (lane==0) red[wid]=z;
  __syncthreads();
  if (t==0){ float r=0; for (int k=0;k<16;k++) r+=red[k]; red[0]=r; }
  __syncthreads();
  float invZ = 1.f/red[0];
  for (int i=t;i<n;i+=1024) wts[i] = expf((scores[i]-M)*(1.f/16.f))*invZ;
}

// ---------------- f16 MFMA GEMM (TN): C[M,N] = A[M,K] @ B[N,K]^T ----------------
// 128x128 tile, BK=64, 256 threads (4 waves, 2x2 of 64x64), 16x16x32 f16 MFMA.
// XCD-aware swizzle: blockIdx.x == lin%8 == XCD; band = bx + 8*(by>>sh), nt = by&(ntc-1)
// -> all N-tiles of an A-band run consecutively on ONE XCD (A fetched once per L2).
// Fused als/ald partials WITHOUT atomics: per-block LDS reduce -> coalesced store of
// per-tile partials alsp/aldp[nt][m]; combined by als_combine kernel.
__launch_bounds__(256)
__global__ void gemm_f16(const unsigned short* __restrict__ A,
                         const unsigned short* __restrict__ B,
                         unsigned short* __restrict__ C, int M, int N, int K,
                         const float* __restrict__ addCol,   // obW or null
                         const float* __restrict__ vCol,     // VoW
                         const float* __restrict__ wRow,     // wts
                         const float* __restrict__ a_src,    // [N] flat
                         const float* __restrict__ a_dst,
                         float* __restrict__ alsp,           // [ntc][M] partials
                         float* __restrict__ aldp)
{
  __shared__ short lds[2*128*64];
  short* As = lds;
  short* Bs = lds + 128*64;

  const int ntc = N >> 7;                 // N-tiles (pow2: 8 or 2)
  const int sh  = __popc(ntc - 1);
  const int g   = blockIdx.y >> sh;
  const int nt  = blockIdx.y & (ntc - 1);
  const int band = blockIdx.x + (g << 3); // bx + 8*g
  if (band * 128 >= M) return;

  const int t = threadIdx.x;
  const int w = t>>6, l = t&63;
  const int bm = band*128, bn = nt*128;
  const int wr = (w>>1)*64, wc = (w&1)*64;
  const int half = w & 1;                 // which 64-col half of the tile

  f32x4v acc[4][4];
#pragma unroll
  for (int i=0;i<4;i++)
#pragma unroll
    for (int j=0;j<4;j++) acc[i][j] = (f32x4v){0.f,0.f,0.f,0.f};

  const unsigned short* Ap[4]; const unsigned short* Bp[4];
  int ldsOff[4];
#pragma unroll
  for (int q=0;q<4;q++){
    int p  = (w*4+q)*64 + l;       // phys 16B-chunk
    int r  = p>>3, pc = p&7;
    int kc = (pc ^ (r&7))*8;       // logical k element offset (XOR swizzle)
    int rowA = bm + r; if (rowA > M-1) rowA = M-1;
    Ap[q] = A + (size_t)rowA*K + kc;
    Bp[q] = B + (size_t)(bn+r)*K + kc;
    ldsOff[q] = (w*4+q)*64*8;      // shorts (wave-uniform base; lane spreads x16B)
  }

  for (int k0=0; k0<K; k0+=64){
#pragma unroll
    for (int q=0;q<4;q++) async_copy16(As + ldsOff[q], Ap[q] + k0);
#pragma unroll
    for (int q=0;q<4;q++) async_copy16(Bs + ldsOff[q], Bp[q] + k0);
    __syncthreads();

    const int q4 = l>>4, m16 = l&15;
#pragma unroll
    for (int ks=0; ks<2; ks++){
      f16x8 af[4], bf[4];
      const int c = ks*4 + q4;
#pragma unroll
      for (int i=0;i<4;i++){
        int ra = wr + i*16 + m16;
        af[i] = *(const f16x8*)&As[ra*64 + ((c ^ (ra&7))*8)];
        int rb = wc + i*16 + m16;
        bf[i] = *(const f16x8*)&Bs[rb*64 + ((c ^ (rb&7))*8)];
      }
#pragma unroll
      for (int i=0;i<4;i++)
#pragma unroll
        for (int j=0;j<4;j++)
          acc[i][j] = __builtin_amdgcn_mfma_f32_16x16x32_f16(af[i], bf[j], acc[i][j], 0,0,0);
    }
    __syncthreads();
  }

  // epilogue: C/D layout col = l&15, row = (l>>4)*4 + r ; f32 math then f16 store.
  // als/ald partial per row via 16-lane shfl reduce; cross-wave (column halves)
  // combined through LDS (reused), then one coalesced 128-wide store.
  float* sred = (float*)lds;          // [2][128]
  float* dred = sred + 256;           // [2][128]
  const int q4 = l>>4, m16 = l&15;
  float asv[4], adv[4];
#pragma unroll
  for (int j=0;j<4;j++){
    int n = bn + wc + j*16 + m16;
    asv[j] = a_src[n];
    adv[j] = a_dst[n];
  }
#pragma unroll
  for (int i=0;i<4;i++){
#pragma unroll
    for (int r=0;r<4;r++){
      int rloc = wr + i*16 + q4*4 + r;
      int m = bm + rloc;
      float wrow = addCol ? wRow[m < M ? m : M-1] : 0.f;
      float vj[4];
#pragma unroll
      for (int j=0;j<4;j++){
        int n = bn + wc + j*16 + m16;
        float v = acc[i][j][r];
        if (addCol) v += addCol[n] + wrow*vCol[n];
        vj[j] = v;
      }
      if (m < M){
        unsigned short* crow = C + (size_t)m*N;
#pragma unroll
        for (int j=0;j<4;j++) crow[bn + wc + j*16 + m16] = f2hu(vj[j]);
      }
      float s = vj[0]*asv[0] + vj[1]*asv[1] + vj[2]*asv[2] + vj[3]*asv[3];
      float d = vj[0]*adv[0] + vj[1]*adv[1] + vj[2]*adv[2] + vj[3]*adv[3];
#pragma unroll
      for (int o=1;o<16;o<<=1){ s += __shfl_xor(s,o); d += __shfl_xor(d,o); }
      if (m16 == 0){
        sred[half*128 + rloc] = s;
        dred[half*128 + rloc] = d;
      }
    }
  }
  __syncthreads();
  if (t < 128){
    int m = bm + t;
    if (m < M){
      alsp[(size_t)nt*M + m] = sred[t] + sred[128+t];
      aldp[(size_t)nt*M + m] = dred[t] + dred[128+t];
    }
  }
}

// combine per-tile partials -> als/ald [m*H+hh]; each head spans 2 column tiles
__global__ void als_combine(const float* __restrict__ alsp, const float* __restrict__ aldp,
                            float* __restrict__ als, float* __restrict__ ald, int M, int H){
  int idx = blockIdx.x*256 + threadIdx.x;
  if (idx >= M*H) return;
  int m = idx / H, hh = idx - m*H;
  als[idx] = alsp[(size_t)(2*hh)*M + m] + alsp[(size_t)(2*hh+1)*M + m];
  ald[idx] = aldp[(size_t)(2*hh)*M + m] + aldp[(size_t)(2*hh+1)*M + m];
}

template<int H>
__global__ void we_kernel(const float* __restrict__ We, const float* __restrict__ a_edge,
                          float* __restrict__ we){
  int wid = threadIdx.x>>6, lane = threadIdx.x&63;
  if (wid < H){
    const float4* w4 = (const float4*)(We + wid*256);
    const float4* a4 = (const float4*)(a_edge + wid*256);
    float4 a = w4[lane], b = a4[lane];
    float v = a.x*b.x + a.y*b.y + a.z*b.z + a.w*b.w;
    v = wsum(v);
    if (lane==0) we[wid]=v;
  }
}

// ---------------- fused alpha-softmax + aggregate + bias + LN + ReLU ----------------
// ONE WAVE PER NODE (4 waves/block, no __syncthreads). h is f16.
// outb != null -> write f16 (feeds next GEMM); else f32 to outf.
template<int H>
__launch_bounds__(256)
__global__ void gat_agg_ln_wave(const unsigned short* __restrict__ hmat,
                           const float* __restrict__ als, const float* __restrict__ ald,
                           const int* __restrict__ off, const int* __restrict__ csr_src,
                           const float* __restrict__ csr_ea, const float* __restrict__ loop_attr,
                           const float* __restrict__ we,
                           const float* __restrict__ bias,
                           const float* __restrict__ ln_g, const float* __restrict__ ln_b,
                           float* __restrict__ outf, unsigned short* __restrict__ outb, int n)
{
  constexpr int OUT = 256*H;      // 1024 or 256
  constexpr int CPL = OUT/64;     // channels per lane: 16 or 4
  const int wv = threadIdx.x>>6, lane = threadIdx.x&63;
  const int i = blockIdx.x*4 + wv;
  __shared__ float wbuf_s[4][64*H];
  __shared__ int   sbuf_s[4][64];
  if (i >= n) return;
  float* wbuf = wbuf_s[wv];
  int*   sbuf = sbuf_s[wv];

  const int begin = off[i];
  const int deg   = off[i+1]-begin;
  const int S     = deg + 1;           // + self-loop

  float aldi[H], wei[H];
#pragma unroll
  for (int hh=0;hh<H;hh++){ aldi[hh]=ald[(size_t)i*H+hh]; wei[hh]=we[hh]; }
  const float lea = loop_attr[i];

  const int head = (lane*CPL) >> 8;    // which head this lane's channels belong to
  const int c0   = lane*CPL;
  float acc[CPL];
#pragma unroll
  for (int c=0;c<CPL;c++) acc[c]=0.f;

  if (S <= 64){
    // ---- fast path: lane == edge slot; alphas live in registers ----
    int src = i; float ev = lea;
    if (lane < deg){ src = csr_src[begin+lane]; ev = csr_ea[begin+lane]; }
    const bool act = lane < S;
    float a[H];
#pragma unroll
    for (int hh=0;hh<H;hh++){
      float v = als[(size_t)src*H+hh] + aldi[hh] + ev*wei[hh];
      a[hh] = v>0.f ? v : 0.2f*v;
    }
#pragma unroll
    for (int hh=0;hh<H;hh++){
      float M = wmax_all(act ? a[hh] : -INFINITY);
      float e = act ? __expf(a[hh]-M) : 0.f;
      float Z = wsum_all(e);
      wbuf[lane*H+hh] = e / (Z + 1e-16f);
    }
    sbuf[lane] = src;
    for (int j=0;j<S;j++){
      int sj = sbuf[j];
      float wj = wbuf[j*H+head];
      const unsigned short* row = hmat + (size_t)sj*OUT + c0;
      if constexpr (CPL==16){
        u16x8 r0 = *(const u16x8*)(row);
        u16x8 r1 = *(const u16x8*)(row+8);
#pragma unroll
        for (int c=0;c<8;c++){
          acc[c]   = fmaf(wj, hu2f(r0[c]), acc[c]);
          acc[8+c] = fmaf(wj, hu2f(r1[c]), acc[8+c]);
        }
      } else {
        ushort4 r = *(const ushort4*)(row);
        acc[0]=fmaf(wj,hu2f(r.x),acc[0]); acc[1]=fmaf(wj,hu2f(r.y),acc[1]);
        acc[2]=fmaf(wj,hu2f(r.z),acc[2]); acc[3]=fmaf(wj,hu2f(r.w),acc[3]);
      }
    }
  } else {
    // ---- slow path (deg >= 64, vanishingly rare): chunked recompute ----
    float rm[H];
#pragma unroll
    for (int hh=0;hh<H;hh++) rm[hh] = -INFINITY;
    for (int s=lane; s<S; s+=64){
      int src = (s<deg)? csr_src[begin+s] : i;
      float ev = (s<deg)? csr_ea[begin+s] : lea;
#pragma unroll
      for (int hh=0;hh<H;hh++){
        float v = als[(size_t)src*H+hh] + aldi[hh] + ev*wei[hh];
        v = v>0.f? v : 0.2f*v;
        rm[hh] = fmaxf(rm[hh], v);
      }
    }
    float M[H], es[H];
#pragma unroll
    for (int hh=0;hh<H;hh++){ M[hh]=wmax_all(rm[hh]); es[hh]=0.f; }
    for (int s=lane; s<S; s+=64){
      int src = (s<deg)? csr_src[begin+s] : i;
      float ev = (s<deg)? csr_ea[begin+s] : lea;
#pragma unroll
      for (int hh=0;hh<H;hh++){
        float v = als[(size_t)src*H+hh] + aldi[hh] + ev*wei[hh];
        v = v>0.f? v : 0.2f*v;
        es[hh] += __expf(v - M[hh]);
      }
    }
    float invZ[H];
#pragma unroll
    for (int hh=0;hh<H;hh++) invZ[hh] = 1.f/(wsum_all(es[hh]) + 1e-16f);
    for (int cb=0; cb<S; cb+=64){
      int m = min(64, S-cb);
      int s = cb + lane;
      if (s < S){
        int src = (s<deg)? csr_src[begin+s] : i;
        float ev = (s<deg)? csr_ea[begin+s] : lea;
        sbuf[lane] = src;
#pragma unroll
        for (int hh=0;hh<H;hh++){
          float v = als[(size_t)src*H+hh] + aldi[hh] + ev*wei[hh];
          v = v>0.f? v : 0.2f*v;
          wbuf[lane*H+hh] = __expf(v - M[hh]) * invZ[hh];
        }
      }
      for (int j=0;j<m;j++){
        int sj = sbuf[j];
        float wj = wbuf[j*H+head];
        const unsigned short* row = hmat + (size_t)sj*OUT + c0;
        if constexpr (CPL==16){
          u16x8 r0 = *(const u16x8*)(row);
          u16x8 r1 = *(const u16x8*)(row+8);
#pragma unroll
          for (int c=0;c<8;c++){
            acc[c]   = fmaf(wj, hu2f(r0[c]), acc[c]);
            acc[8+c] = fmaf(wj, hu2f(r1[c]), acc[8+c]);
          }
        } else {
          ushort4 r = *(const ushort4*)(row);
          acc[0]=fmaf(wj,hu2f(r.x),acc[0]); acc[1]=fmaf(wj,hu2f(r.y),acc[1]);
          acc[2]=fmaf(wj,hu2f(r.z),acc[2]); acc[3]=fmaf(wj,hu2f(r.w),acc[3]);
        }
      }
    }
  }

  // ---- bias + LayerNorm + ReLU (wave-level) ----
  float vals[CPL];
  float ls=0.f;
#pragma unroll
  for (int c=0;c<CPL;c+=4){
    float4 b4 = *(const float4*)(bias + c0 + c);
    vals[c]=acc[c]+b4.x; vals[c+1]=acc[c+1]+b4.y; vals[c+2]=acc[c+2]+b4.z; vals[c+3]=acc[c+3]+b4.w;
    ls += vals[c]+vals[c+1]+vals[c+2]+vals[c+3];
  }
  float mu = wsum_all(ls) * (1.f/OUT);
  float lv=0.f;
#pragma unroll
  for (int c=0;c<CPL;c++){ float d=vals[c]-mu; lv += d*d; }
  float inv = rsqrtf(wsum_all(lv)*(1.f/OUT) + 1e-5f);

  if (outb){
    if constexpr (CPL==16){
#pragma unroll
      for (int c=0;c<CPL;c+=8){
        u16x8 o;
#pragma unroll
        for (int k=0;k<8;k++){
          float g = ln_g[c0+c+k], b = ln_b[c0+c+k];
          o[k] = f2hu(fmaxf((vals[c+k]-mu)*inv*g + b, 0.f));
        }
        *(u16x8*)(outb + (size_t)i*OUT + c0 + c) = o;
      }
    } else {
      ushort4 o;
      o.x = f2hu(fmaxf((vals[0]-mu)*inv*ln_g[c0+0] + ln_b[c0+0], 0.f));
      o.y = f2hu(fmaxf((vals[1]-mu)*inv*ln_g[c0+1] + ln_b[c0+1], 0.f));
      o.z = f2hu(fmaxf((vals[2]-mu)*inv*ln_g[c0+2] + ln_b[c0+2], 0.f));
      o.w = f2hu(fmaxf((vals[3]-mu)*inv*ln_g[c0+3] + ln_b[c0+3], 0.f));
      *(ushort4*)(outb + (size_t)i*OUT + c0) = o;
    }
  } else {
#pragma unroll
    for (int c=0;c<CPL;c+=4){
      float4 g4 = *(const float4*)(ln_g + c0 + c);
      float4 b4 = *(const float4*)(ln_b + c0 + c);
      float4 o;
      o.x = fmaxf((vals[c+0]-mu)*inv*g4.x + b4.x, 0.f);
      o.y = fmaxf((vals[c+1]-mu)*inv*g4.y + b4.y, 0.f);
      o.z = fmaxf((vals[c+2]-mu)*inv*g4.z + b4.z, 0.f);
      o.w = fmaxf((vals[c+3]-mu)*inv*g4.w + b4.w, 0.f);
      *(float4*)(outf + (size_t)i*OUT + c0 + c) = o;
    }
  }
}

// ---------------- mean pool + classifier ----------------
__global__ void colsum_kernel(const float* __restrict__ h2, float* __restrict__ gsum, int n){
  int c = threadIdx.x; // 256
  float acc=0;
  for (int i=blockIdx.x;i<n;i+=gridDim.x) acc += h2[(size_t)i*256 + c];
  atomicAdd(&gsum[c], acc);
}

__launch_bounds__(128)
__global__ void cls_kernel(const float* __restrict__ gsum,
                           const float* __restrict__ w1, const float* __restrict__ b1,
                           const float* __restrict__ w2, const float* __restrict__ b2,
                           float* __restrict__ outp){
  __shared__ float g[256];
  __shared__ float hid[128];
  int t = threadIdx.x;
  g[t]     = gsum[t]    *(1.f/N_NODES);
  g[t+128] = gsum[t+128]*(1.f/N_NODES);
  __syncthreads();
  float a = b1[t];
  for (int c=0;c<256;c++) a = fmaf(g[c], w1[c*128+t], a);
  hid[t] = fmaxf(a, 0.f);
  __syncthreads();
  if (t<2){
    float o = b2[t];
    for (int j=0;j<128;j++) o = fmaf(hid[j], w2[j*2+t], o);
    outp[t] = o;
  }
}

// ---------------- launch ----------------
extern "C" void kernel_launch(void* const* d_in, const int* in_sizes, int n_in,
                              void* d_out, int out_size, void* d_ws, size_t ws_size,
                              hipStream_t stream)
{
  const float* x      = (const float*)d_in[0];
  const int*   ei     = (const int*)  d_in[1];
  const float* ea     = (const float*)d_in[2];
  const float* ca_qw  = (const float*)d_in[3];
  const float* ca_kw  = (const float*)d_in[5];
  const float* ca_kb  = (const float*)d_in[6];
  const float* ca_vw  = (const float*)d_in[7];
  const float* ca_vb  = (const float*)d_in[8];
  const float* ca_ow  = (const float*)d_in[9];
  const float* ca_ob  = (const float*)d_in[10];
  const float* g0_w   = (const float*)d_in[11];
  const float* g0_ew  = (const float*)d_in[12];
  const float* g0_as  = (const float*)d_in[13];
  const float* g0_ad  = (const float*)d_in[14];
  const float* g0_ae  = (const float*)d_in[15];
  const float* g0_b   = (const float*)d_in[16];
  const float* ln0_g  = (const float*)d_in[17];
  const float* ln0_b  = (const float*)d_in[18];
  const float* g1_w   = (const float*)d_in[19];
  const float* g1_ew  = (const float*)d_in[20];
  const float* g1_as  = (const float*)d_in[21];
  const float* g1_ad  = (const float*)d_in[22];
  const float* g1_ae  = (const float*)d_in[23];
  const float* g1_b   = (const float*)d_in[24];
  const float* ln1_g  = (const float*)d_in[25];
  const float* ln1_b  = (const float*)d_in[26];
  const float* g2_w   = (const float*)d_in[27];
  const float* g2_ew  = (const float*)d_in[28];
  const float* g2_as  = (const float*)d_in[29];
  const float* g2_ad  = (const float*)d_in[30];
  const float* g2_ae  = (const float*)d_in[31];
  const float* g2_b   = (const float*)d_in[32];
  const float* ln2_g  = (const float*)d_in[33];
  const float* ln2_b  = (const float*)d_in[34];
  const float* cls_w1 = (const float*)d_in[35];
  const float* cls_b1 = (const float*)d_in[36];
  const float* cls_w2 = (const float*)d_in[37];
  const float* cls_b2 = (const float*)d_in[38];
  float* outp = (float*)d_out;

  const int N = N_NODES, E = N_EDGES;

  char* base = (char*)d_ws;
  size_t o = 0;
  auto alloc = [&](size_t bytes)->void*{
    void* p = base + o;
    o += (bytes + 255) & ~(size_t)255;
    return p;
  };
  unsigned short* hF   = (unsigned short*)alloc((size_t)N*1024*2); // GEMM output h (f16)
  unsigned short* Af   = (unsigned short*)alloc((size_t)N*1280*2); // f16 activations (x, then agg out)
  float*          h2   = (float*)         alloc((size_t)N*256*4);  // layer-2 agg out (f32)
  unsigned short* Wt   = (unsigned short*)alloc((size_t)1280*1024*2);
  float* alsp      = (float*)alloc((size_t)8*N*4);    // per-tile partials
  float* aldp      = (float*)alloc((size_t)8*N*4);
  float* als       = (float*)alloc((size_t)2*N*4*4);  // als | ald contiguous
  float* ald       = als + (size_t)N*4;
  float* scores    = (float*)alloc((size_t)N*4);
  float* wts       = (float*)alloc((size_t)N*4);
  int*   cnt       = (int*)  alloc((size_t)N*4);
  float* easum     = (float*)alloc((size_t)N*4);
  int*   off       = (int*)  alloc((size_t)(N+1)*4);
  int*   fill      = (int*)  alloc((size_t)N*4);
  int*   csr_src   = (int*)  alloc((size_t)E*4);
  float* csr_ea    = (float*)alloc((size_t)E*4);
  float* loop_attr = (float*)alloc((size_t)N*4);
  float* Kv        = (float*)alloc(256*4);
  float* Vv        = (float*)alloc(256*4);
  float* qK        = (float*)alloc(1280*4);
  float* Vo        = (float*)alloc(1280*4);
  float* obW       = (float*)alloc(1024*4);
  float* VoW       = (float*)alloc(1024*4);
  float* web       = (float*)alloc(16*4);
  float* gsum      = (float*)alloc(256*4);

  hipMemsetAsync(cnt,   0, (size_t)N*4, stream);
  hipMemsetAsync(easum, 0, (size_t)N*4, stream);
  hipMemsetAsync(fill,  0, (size_t)N*4, stream);
  hipMemsetAsync(gsum,  0, 256*4,       stream);

  // ---- edge preprocessing (CSR by dst) ----
  int eblocks = (E + 255)/256;
  edge_count_kernel<<<eblocks,256,0,stream>>>(ei, ea, cnt, easum, E);
  scan_kernel<<<1,1024,0,stream>>>(cnt, easum, off, loop_attr, N);
  edge_fill_kernel<<<eblocks,256,0,stream>>>(ei, ea, off, fill, csr_src, csr_ea, E);

  // ---- activations to f16 ----
  x_to_f16<<<2048,256,0,stream>>>(x, Af);

  // ---- cross-attention, rank-1 collapsed ----
  kv_kernel<<<1,256,0,stream>>>(x, ca_kw, ca_kb, ca_vw, ca_vb, Kv, Vv);
  qkvo_kernel<<<10,256,0,stream>>>(ca_qw, ca_ow, Kv, Vv, qK, Vo);
  obw_kernel<<<4,256,0,stream>>>(ca_ob, Vo, g0_w, obW, VoW);
  scores_kernel<<<(N+3)/4,256,0,stream>>>(Af, qK, scores, N);
  softmax_nodes<<<1,1024,0,stream>>>(scores, wts, N);

  const int mTiles  = (N + 127)/128;      // 157
  const int mGroups = (mTiles + 7)/8;     // 20
  const int NB4 = (N + 3)/4;              // wave-per-node blocks

  // ---- layer 0 ----
  wt_f16_kernel<<<dim3(1280/32, 1024/32),256,0,stream>>>(g0_w, 1280, 1024, Wt);
  gemm_f16<<<dim3(8, mGroups*8),256,0,stream>>>(Af, Wt, hF, N, 1024, 1280, obW, VoW, wts,
                                                g0_as, g0_ad, alsp, aldp);
  als_combine<<<(N*4+255)/256,256,0,stream>>>(alsp, aldp, als, ald, N, 4);
  we_kernel<4><<<1,256,0,stream>>>(g0_ew, g0_ae, web);
  gat_agg_ln_wave<4><<<NB4,256,0,stream>>>(hF, als, ald, off, csr_src, csr_ea, loop_attr,
                                           web, g0_b, ln0_g, ln0_b, nullptr, Af, N);

  // ---- layer 1 ----
  wt_f16_kernel<<<dim3(1024/32, 1024/32),256,0,stream>>>(g1_w, 1024, 1024, Wt);
  gemm_f16<<<dim3(8, mGroups*8),256,0,stream>>>(Af, Wt, hF, N, 1024, 1024, nullptr, nullptr, nullptr,
                                                g1_as, g1_ad, alsp, aldp);
  als_combine<<<(N*4+255)/256,256,0,stream>>>(alsp, aldp, als, ald, N, 4);
  we_kernel<4><<<1,256,0,stream>>>(g1_ew, g1_ae, web);
  gat_agg_ln_wave<4><<<NB4,256,0,stream>>>(hF, als, ald, off, csr_src, csr_ea, loop_attr,
                                           web, g1_b, ln1_g, ln1_b, nullptr, Af, N);

  // ---- layer 2 (1 head, 256 out) ----
  wt_f16_kernel<<<dim3(1024/32, 256/32),256,0,stream>>>(g2_w, 1024, 256, Wt);
  gemm_f16<<<dim3(8, mGroups*2),256,0,stream>>>(Af, Wt, hF, N, 256, 1024, nullptr, nullptr, nullptr,
                                                g2_as, g2_ad, alsp, aldp);
  als_combine<<<(N+255)/256,256,0,stream>>>(alsp, aldp, als, ald, N, 1);
  we_kernel<1><<<1,256,0,stream>>>(g2_ew, g2_ae, web);
  gat_agg_ln_wave<1><<<NB4,256,0,stream>>>(hF, als, ald, off, csr_src, csr_ea, loop_attr,
                                           web, g2_b, ln2_g, ln2_b, h2, nullptr, N);

  // ---- mean pool + classifier ----
  colsum_kernel<<<256,256,0,stream>>>(h2, gsum, N);
  cls_kernel<<<1,128,0,stream>>>(gsum, cls_w1, cls_b1, cls_w2, cls_b2, outp);

  (void)in_sizes; (void)n_in; (void)out_size; (void)ws_size;
}